// Round 23
// baseline (654.120 us; speedup 1.0000x reference)
//
#include <hip/hip_runtime.h>
#include <cstdio>
#include <cstdint>

// ---------------------------------------------------------------------------
// WindowAttention split pipeline, round 23 (= round 22 + two-phase pipelined
// A-staging in gemm2 (MODE 1) with counted vmcnt — phase-1 = ksl 0-11,
// phase-2 = ksl 12-23 stays in flight across the first barrier):
//   prep: wswz32(Wqkv) + wswz32(Wproj) + mask_bits in ONE kernel.
//   gemm_32<3,0>: r22-exact (fused fp32->bf16 conflict-free staging, A
//     persistent LDS frag-major, B streamed 3-buffer, 32x32x16, 64x96 tile).
//   attn: 1 wave/(b,h); Q/K direct from global; V staged->Vt LDS; bitmask.
//   gemm_32<1,1>: proj; A-stage split in two vmcnt-counted phases so the
//     single compute round overlaps half the staging latency.
// Spill tripwire: VGPR=128 + FETCH/WRITE inflation.
// ---------------------------------------------------------------------------

typedef __attribute__((ext_vector_type(8))) short bfrag8;    // 8 bf16 (4 VGPR)
typedef __attribute__((ext_vector_type(4))) float facc4;     // 16x16 acc
typedef __attribute__((ext_vector_type(16))) float facc16;   // 32x32 acc

#define SCALE_Q 0.17677669529663687f
#define PLANE 6422528ull  // 200704 * 32 elems per (t,h) plane

__device__ __forceinline__ unsigned short f2bf(float f) {  // fp32->bf16 RNE
  unsigned int x = __float_as_uint(f);
  x += 0x7fffu + ((x >> 16) & 1u);
  return (unsigned short)(x >> 16);
}

__device__ __forceinline__ void gload_lds16(const void* g, void* l) {
  __builtin_amdgcn_global_load_lds(
      (const __attribute__((address_space(1))) unsigned int*)g,
      (__attribute__((address_space(3))) unsigned int*)l,
      16, 0, 0);
}

// ---- merged prep: weights -> bf16 frag-major (32x32x16) + mask bitmasks ---
// wswz32: fid = (col/32)*24 + k/16; lane lc: col=(fid/24)*32+(lc&31),
// k=(fid%24)*16+(lc>>5)*8; 512 shorts per frag.
__global__ void __launch_bounds__(256) prep_kernel(
    const float* __restrict__ wq, const float* __restrict__ wp,
    const float* __restrict__ mask,
    unsigned short* __restrict__ Bfq, unsigned short* __restrict__ Bfp,
    unsigned long long* __restrict__ bits) {
  const int blk = blockIdx.x;
  if (blk < 288) {
    const float* w = (blk < 216) ? wq : wp;
    unsigned short* Bf = (blk < 216) ? Bfq : Bfp;
    const int t = ((blk < 216) ? blk : blk - 216) * 256 + threadIdx.x;
    const int fid = t >> 6, lc = t & 63;
    const int cg = fid / 24, ksl = fid - cg * 24;
    const int col = cg * 32 + (lc & 31);
    const int k = ksl * 16 + (lc >> 5) * 8;
    const float* src = w + (size_t)col * 384 + k;
    unsigned short* dst = Bf + ((size_t)fid << 9) + (lc << 3);
#pragma unroll
    for (int j = 0; j < 8; ++j) dst[j] = f2bf(src[j]);
  } else {
    const int idx = (blk - 288) * 256 + threadIdx.x;  // 0..4095
    const int wdw = idx >> 6, m = idx & 63;
    unsigned long long bm = 0ull;
    if (m < 49) {
      const float* mp = mask + (size_t)wdw * 2401 + (size_t)m * 49;
      for (int n = 0; n < 49; ++n)
        if (mp[n] > -50.f) bm |= (1ull << n);
    }
    bits[idx] = bm;
  }
}

// ---------------------------------------------------------------------------
// gemm_32: C = A * B^T (+bias). 32x32x16 MFMA, wave tile 64 x 96,
// 8 waves = 2M x 4N, acc[2][3] f32x16, 3-buffer B register rotation.
// MODE 0: A = fp32 x (fused cvt, conflict-free chunk map); planar qkv out.
// MODE 1: A = bf16 via global_load_lds in TWO vmcnt-counted phases
//         (ksl 0-11 then 12-23); fp32 out (+bias).
// A-frag fid = (row/32)*24 + kslot; lane: row=rg*32+(l&31), k=ksl*16+(l>>5)*8.
// C/D map (verified): col = lane&31, row = (r&3) + 8*(r>>2) + 4*(lane>>5).
// ---------------------------------------------------------------------------
#define LB32(dst, ks_)                                                         \
  {                                                                            \
    _Pragma("unroll") for (int ni = 0; ni < 3; ++ni)                           \
        dst[ni] = *(const bfrag8*)(                                            \
            Bf + ((size_t)((cg0 + ni) * 24 + (ks_)) << 9) + (lane << 3));      \
  }

#define MF32(bb, ks_)                                                          \
  {                                                                            \
    const bfrag8 af0 = *(const bfrag8*)(Ab + ((size_t)(ks_) << 10));           \
    const bfrag8 af1 = *(const bfrag8*)(Ab + ((size_t)(24 + (ks_)) << 10));    \
    _Pragma("unroll") for (int ni = 0; ni < 3; ++ni) {                         \
      acc[0][ni] = __builtin_amdgcn_mfma_f32_32x32x16_bf16(af0, bb[ni],        \
                                                           acc[0][ni], 0, 0, 0);\
      acc[1][ni] = __builtin_amdgcn_mfma_f32_32x32x16_bf16(af1, bb[ni],        \
                                                           acc[1][ni], 0, 0, 0);\
    }                                                                          \
  }

template <int NR, int MODE, int SWZ>
__global__ void __launch_bounds__(512, 1) gemm_32(
    const float* __restrict__ Af32, const unsigned short* __restrict__ Abf,
    const unsigned short* __restrict__ Bf, const float* __restrict__ bias,
    unsigned short* __restrict__ qkv, float* __restrict__ f_out) {
  __shared__ __align__(16) unsigned short Alds[128 * 384];  // 96 KB frag-major

  int bid = blockIdx.x;
  bid = (bid & 7) * SWZ + (bid >> 3);      // XCD-contiguous (1568 = 8*196)
  const int tid = threadIdx.x;
  const int lane = tid & 63, w = tid >> 6;
  const int wr = w >> 2, wc = w & 3;       // 2 M-halves x 4 N-quarters
  const int l31 = lane & 31, l5 = lane >> 5;
  const size_t a_row0 = (size_t)bid * 128;

  if (MODE == 0) {
    // fused fp32 -> bf16 staging, conflict-free chunk map:
    // chunk c = tid + j*512, fid = w + j*8 (wave-uniform), write base+lane*16.
#pragma unroll
    for (int j = 0; j < 12; ++j) {
      const int fid = w + j * 8;
      const int rg = fid / 24, ksl = fid - rg * 24;
      const int row = rg * 32 + l31;
      const int k = ksl * 16 + l5 * 8;
      const float* src = Af32 + (a_row0 + row) * 384 + k;
      const float4 v0 = *(const float4*)(src);
      const float4 v1 = *(const float4*)(src + 4);
      bfrag8 h;
      h[0] = (short)f2bf(v0.x); h[1] = (short)f2bf(v0.y);
      h[2] = (short)f2bf(v0.z); h[3] = (short)f2bf(v0.w);
      h[4] = (short)f2bf(v1.x); h[5] = (short)f2bf(v1.y);
      h[6] = (short)f2bf(v1.z); h[7] = (short)f2bf(v1.w);
      *(bfrag8*)((char*)Alds + ((w << 10) + (j << 13)) + (lane << 4)) = h;
    }
    __syncthreads();
  } else {
    // bf16 source in TWO phases of 6 gload_lds each. Linear index
    // L = w*6 + j (wave-uniform): rg = L/12, ksl = L%12 (+12 for phase 2),
    // fid = rg*24 + ksl; LDS dest = fid<<10 (wave-uniform, lane*16 implied).
#pragma unroll
    for (int j = 0; j < 6; ++j) {           // phase 1: ksl 0-11
      const int L = w * 6 + j;
      const int rg = L / 12, ksl = L - rg * 12;
      gload_lds16(Abf + (a_row0 + rg * 32 + l31) * 384 + ksl * 16 + l5 * 8,
                  (char*)Alds + ((size_t)(rg * 24 + ksl) << 10));
    }
#pragma unroll
    for (int j = 0; j < 6; ++j) {           // phase 2: ksl 12-23
      const int L = w * 6 + j;
      const int rg = L / 12, ksl = L - rg * 12 + 12;
      gload_lds16(Abf + (a_row0 + rg * 32 + l31) * 384 + ksl * 16 + l5 * 8,
                  (char*)Alds + ((size_t)(rg * 24 + ksl) << 10));
    }
    // phase-1 landed (6 newest = phase-2 stay in flight), then join waves
    asm volatile("s_waitcnt vmcnt(6)" ::: "memory");
    __builtin_amdgcn_sched_barrier(0);
    __builtin_amdgcn_s_barrier();
    __builtin_amdgcn_sched_barrier(0);
  }

  // af source: fid = (wr*2 + mi)*24 + ksl
  const char* Ab = (const char*)Alds + ((size_t)(wr * 48) << 10) + (lane << 4);

  for (int rnd = 0; rnd < NR; ++rnd) {
    const int cg0 = (rnd * 4 + wc) * 3;    // first 32-col group of this wave
    facc16 acc[2][3];
#pragma unroll
    for (int mi = 0; mi < 2; ++mi)
#pragma unroll
      for (int ni = 0; ni < 3; ++ni)
#pragma unroll
        for (int r = 0; r < 16; ++r) acc[mi][ni][r] = 0.f;

    bfrag8 bA[3], bB[3], bC[3];
    LB32(bA, 0);
    LB32(bB, 1);
    LB32(bC, 2);
#pragma unroll 1   // ROLLED: prevents load hoisting / register blowup
    for (int ks = 0; ks < 24; ks += 3) {
      if (MODE == 1 && ks == 12) {
        // phase-2 A landed before any wave reads ksl >= 12
        asm volatile("s_waitcnt vmcnt(0)" ::: "memory");
        __builtin_amdgcn_sched_barrier(0);
        __builtin_amdgcn_s_barrier();
        __builtin_amdgcn_sched_barrier(0);
      }
      MF32(bA, ks);
      if (ks + 3 < 24) LB32(bA, ks + 3);
      MF32(bB, ks + 1);
      if (ks + 4 < 24) LB32(bB, ks + 4);
      MF32(bC, ks + 2);
      if (ks + 5 < 24) LB32(bC, ks + 5);
    }

    // ---- epilogue: col = (cg0+ni)*32 + l31, m = a_row0 + wr*64 + mi*32 +
    //      (r&3) + 8*(r>>2) + 4*l5
    if (MODE == 0) {
#pragma unroll
      for (int ni = 0; ni < 3; ++ni) {
        const int j0 = (cg0 + ni) * 32;               // 32-aligned col base
        const int t = j0 / 384;
        const int rj = j0 - t * 384;
        const int h = rj >> 5;
        unsigned short* pl = qkv + (size_t)(t * 12 + h) * PLANE + l31;
        const float bvv = bias[j0 + l31];
        const float sc = (t == 0) ? SCALE_Q : 1.0f;
#pragma unroll
        for (int mi = 0; mi < 2; ++mi)
#pragma unroll
          for (int r = 0; r < 16; ++r) {
            const size_t m = a_row0 + wr * 64 + mi * 32 +
                             (r & 3) + 8 * (r >> 2) + 4 * l5;
            pl[m * 32] = f2bf((acc[mi][ni][r] + bvv) * sc);
          }
      }
    } else {
#pragma unroll
      for (int ni = 0; ni < 3; ++ni) {
        const int col = (cg0 + ni) * 32 + l31;
        const float bvv = bias[col];
#pragma unroll
        for (int mi = 0; mi < 2; ++mi)
#pragma unroll
          for (int r = 0; r < 16; ++r) {
            const size_t m = a_row0 + wr * 64 + mi * 32 +
                             (r & 3) + 8 * (r >> 2) + 4 * l5;
            f_out[m * 384 + col] = acc[mi][ni][r] + bvv;
          }
      }
    }
  }
}

// ---------------------------------------------------------------------------
// Attention: one wave per (window b, head h). Planar Q/K/V; Q/K frags direct
// from global; V staged to LDS transposed+swizzled; bitmask softmax.
// ---------------------------------------------------------------------------
__global__ void __launch_bounds__(64) attn_kernel(
    const unsigned short* __restrict__ QKV,        // 36 planes
    const unsigned long long* __restrict__ mbits,  // (64, 64)
    unsigned short* __restrict__ Og) {             // (4096*49, 384) bf16
  __shared__ unsigned short Vt[32 * 64];   // [d][n], byte-XOR swizzled
  __shared__ unsigned short Ps[64 * 64];   // [m][n], byte-XOR swizzled

  const int bid = blockIdx.x;
  const int b = bid / 12, h = bid - b * 12;
  const int lane = threadIdx.x;
  const int l15 = lane & 15, l4 = lane >> 4;

  const bfrag8 z8 = {0, 0, 0, 0, 0, 0, 0, 0};
  const facc4 fz = {0.f, 0.f, 0.f, 0.f};

  const size_t wb = (size_t)b * 49 * 32;
  const unsigned short* Qp = QKV + (size_t)h * PLANE + wb;
  const unsigned short* Kp = QKV + (size_t)(12 + h) * PLANE + wb;
  const unsigned short* Vp = QKV + (size_t)(24 + h) * PLANE + wb;

  // zero ALL of Vt (4096 B): pad cols n in [49,64) must be 0
#pragma unroll
  for (int i = 0; i < 4; ++i)
    *(bfrag8*)((char*)Vt + (lane + i * 64) * 16) = z8;

  // stage V -> Vt transposed (196 real 16B chunks)
#pragma unroll
  for (int i = 0; i < 4; ++i) {
    const int c = lane + i * 64;
    if (c < 196) {
      const bfrag8 vv = *(const bfrag8*)(Vp + c * 8);
      const int n = c >> 2, cc = c & 3;
      const int d0 = cc * 8;
#pragma unroll
      for (int jj = 0; jj < 8; ++jj) {
        const int d = d0 + jj;
        *(unsigned short*)((char*)Vt + (((d << 7) + (n << 1)) ^ ((d & 7) << 4))) =
            (unsigned short)vv[jj];
      }
    }
  }
  __syncthreads();

  // S = Q K^T : frags direct from global. frag[row=l15][k=l4*8+j]
  facc4 s[4][4];
  {
    bfrag8 qa[4], kf[4];
#pragma unroll
    for (int mi = 0; mi < 4; ++mi)
      qa[mi] = *(const bfrag8*)((const char*)Qp + (mi * 16 + l15) * 64 + l4 * 16);
#pragma unroll
    for (int ni = 0; ni < 4; ++ni)
      kf[ni] = *(const bfrag8*)((const char*)Kp + (ni * 16 + l15) * 64 + l4 * 16);
#pragma unroll
    for (int mi = 0; mi < 4; ++mi)
#pragma unroll
      for (int ni = 0; ni < 4; ++ni)
        s[mi][ni] = __builtin_amdgcn_mfma_f32_16x16x32_bf16(qa[mi], kf[ni], fz, 0, 0, 0);
  }

  // bitmask softmax. acc layout: n = ni*16 + l15, m = mi*16 + l4*4 + r
  const unsigned long long* mb = mbits + (size_t)(b & 63) * 64;
  float rinv[4][4];
#pragma unroll
  for (int mi = 0; mi < 4; ++mi)
#pragma unroll
    for (int r = 0; r < 4; ++r) {
      const int m = mi * 16 + l4 * 4 + r;
      const unsigned long long mw = mb[m];
      float mx = -1e30f;
      int ok[4];
#pragma unroll
      for (int ni = 0; ni < 4; ++ni) {
        const int n = ni * 16 + l15;
        ok[ni] = (int)((mw >> n) & 1ull);
        const float v = ok[ni] ? s[mi][ni][r] : -1e30f;
        mx = fmaxf(mx, v);
      }
      mx = fmaxf(mx, __shfl_xor(mx, 1));
      mx = fmaxf(mx, __shfl_xor(mx, 2));
      mx = fmaxf(mx, __shfl_xor(mx, 4));
      mx = fmaxf(mx, __shfl_xor(mx, 8));
      float sum = 0.f;
#pragma unroll
      for (int ni = 0; ni < 4; ++ni) {
        const float p = ok[ni] ? __expf(s[mi][ni][r] - mx) : 0.f;
        s[mi][ni][r] = p;
        sum += p;
      }
      sum += __shfl_xor(sum, 1);
      sum += __shfl_xor(sum, 2);
      sum += __shfl_xor(sum, 4);
      sum += __shfl_xor(sum, 8);
      rinv[mi][r] = 1.0f / sum;
#pragma unroll
      for (int ni = 0; ni < 4; ++ni) {
        const int n = ni * 16 + l15;
        *(unsigned short*)((char*)Ps + (((m << 7) + (n << 1)) ^ ((m & 7) << 4))) =
            f2bf(s[mi][ni][r]);
      }
    }
  __syncthreads();

  // O = P V (unnormalized), then scale by 1/rowsum
  facc4 o[4][2];
#pragma unroll
  for (int mi = 0; mi < 4; ++mi)
#pragma unroll
    for (int di = 0; di < 2; ++di) o[mi][di] = fz;
#pragma unroll
  for (int kk = 0; kk < 2; ++kk) {
    bfrag8 pa[4], vb[2];
#pragma unroll
    for (int mi = 0; mi < 4; ++mi) {
      const int row = mi * 16 + l15;
      pa[mi] = *(const bfrag8*)((const char*)Ps +
                                (((row << 7) + kk * 64 + (l4 << 4)) ^ ((row & 7) << 4)));
    }
#pragma unroll
    for (int di = 0; di < 2; ++di) {
      const int row = di * 16 + l15;
      vb[di] = *(const bfrag8*)((const char*)Vt +
                                (((row << 7) + kk * 64 + (l4 << 4)) ^ ((row & 7) << 4)));
    }
#pragma unroll
    for (int mi = 0; mi < 4; ++mi)
#pragma unroll
      for (int di = 0; di < 2; ++di)
        o[mi][di] = __builtin_amdgcn_mfma_f32_16x16x32_bf16(pa[mi], vb[di], o[mi][di], 0, 0, 0);
  }

  unsigned short* op = Og + (size_t)b * 18816 + h * 32;  // (b, n, C)
#pragma unroll
  for (int mi = 0; mi < 4; ++mi)
#pragma unroll
    for (int r = 0; r < 4; ++r) {
      const int m = mi * 16 + l4 * 4 + r;
      if (m < 49) {
        const float rs = rinv[mi][r];
#pragma unroll
        for (int di = 0; di < 2; ++di)
          op[(size_t)m * 384 + di * 16 + l15] = f2bf(o[mi][di][r] * rs);
      }
    }
}

// ---------------------------------------------------------------------------
extern "C" void kernel_launch(void* const* d_in, const int* in_sizes, int n_in,
                              void* d_out, int out_size, void* d_ws, size_t ws_size,
                              hipStream_t stream) {
  const float* x      = (const float*)d_in[0];  // (4096, 49, 384)
  const float* mask   = (const float*)d_in[1];  // (64, 49, 49)
  const float* w_qkv  = (const float*)d_in[2];  // (1152, 384)
  const float* b_qkv  = (const float*)d_in[3];  // (1152,)
  const float* w_proj = (const float*)d_in[4];  // (384, 384)
  const float* b_proj = (const float*)d_in[5];  // (384,)
  float* out = (float*)d_out;

  const size_t E = 77070336ull;  // 200704*384  (3*E = 36 planes)
  unsigned short* wsu   = (unsigned short*)d_ws;
  unsigned short* qkvp  = wsu;            // planar qkv: 3E
  unsigned short* o_ws  = wsu + 3 * E;    // (200704, 384) bf16
  unsigned short* Bfq   = wsu + 4 * E;    // frag-major W_qkv bf16 (442368)
  unsigned short* Bfp   = Bfq + 442368ull;  // frag-major W_proj bf16 (147456)
  unsigned long long* mb = (unsigned long long*)(Bfp + 147456ull);  // 4096 u64
  const size_t need = (4 * E + 442368ull + 147456ull) * 2ull + 4096ull * 8ull;
  if (ws_size < need) {
    fprintf(stderr, "[WindowAttention] ws too small: need=%zu have=%zu\n",
            (size_t)need, ws_size);
    return;
  }

  // prep: 288 blocks wswz32 (Bfq 864 frags, Bfp 288 frags) + 16 blocks mask
  prep_kernel<<<304, 256, 0, stream>>>(w_qkv, w_proj, mask, Bfq, Bfp, mb);

  // QKV projection (fused fp32->bf16 A-stage): 1568 blocks, 3 rounds x 96
  gemm_32<3, 0, 196><<<1568, 512, 0, stream>>>(x, nullptr, Bfq, b_qkv,
                                               qkvp, nullptr);

  // attention: one wave per (b, h)
  attn_kernel<<<49152, 64, 0, stream>>>(qkvp, mb, o_ws);

  // output projection: two-phase pipelined A-stage, 1 round x 4 waves x 96
  gemm_32<1, 1, 196><<<1568, 512, 0, stream>>>(nullptr, o_ws, Bfp, b_proj,
                                               nullptr, out);
}

// Round 24
// 650.074 us; speedup vs baseline: 1.0062x; 1.0062x over previous
//
#include <hip/hip_runtime.h>
#include <cstdio>
#include <cstdint>

// ---------------------------------------------------------------------------
// WindowAttention split pipeline, FINAL (= round-18/22 best configuration,
// 650.5/651.4 us measured; round-23 two-phase gemm2 stage was null and is
// reverted):
//   prep: wswz32(Wqkv) + wswz32(Wproj) + mask_bits in ONE kernel.
//   gemm_32<3,0>: A = fp32 x, fused cvt staging with conflict-free chunk map
//     (fid = w + j*8, write base+lane*16); A persistent LDS frag-major
//     (96 KB), ONE barrier; B streamed from global frag-major, 3-buffer
//     register rotation; 8 waves = 2M x 4N, wave tile 64 x 96, 32x32x16 MFMA.
//   attn: 1 wave/(b,h); Q/K direct from global; V staged->Vt LDS; bitmask
//     softmax; P via LDS.
//   gemm_32<1,1>: proj, bf16 A via gload_lds, 3-buffer B-prefetch, fp32 out.
// Session: 929 -> 650 us. Tested-null: counted-vmcnt x2, setprio, B-depth-3,
// af-prefetch. Tested-regression: monolithic fusion, 64-row blocks, 16-wave
// blocks, V^T epilogue, gemm2 operand flip.
// ---------------------------------------------------------------------------

typedef __attribute__((ext_vector_type(8))) short bfrag8;    // 8 bf16 (4 VGPR)
typedef __attribute__((ext_vector_type(4))) float facc4;     // 16x16 acc
typedef __attribute__((ext_vector_type(16))) float facc16;   // 32x32 acc

#define SCALE_Q 0.17677669529663687f
#define PLANE 6422528ull  // 200704 * 32 elems per (t,h) plane

__device__ __forceinline__ unsigned short f2bf(float f) {  // fp32->bf16 RNE
  unsigned int x = __float_as_uint(f);
  x += 0x7fffu + ((x >> 16) & 1u);
  return (unsigned short)(x >> 16);
}

__device__ __forceinline__ void gload_lds16(const void* g, void* l) {
  __builtin_amdgcn_global_load_lds(
      (const __attribute__((address_space(1))) unsigned int*)g,
      (__attribute__((address_space(3))) unsigned int*)l,
      16, 0, 0);
}

// ---- merged prep: weights -> bf16 frag-major (32x32x16) + mask bitmasks ---
// wswz32: fid = (col/32)*24 + k/16; lane lc: col=(fid/24)*32+(lc&31),
// k=(fid%24)*16+(lc>>5)*8; 512 shorts per frag.
__global__ void __launch_bounds__(256) prep_kernel(
    const float* __restrict__ wq, const float* __restrict__ wp,
    const float* __restrict__ mask,
    unsigned short* __restrict__ Bfq, unsigned short* __restrict__ Bfp,
    unsigned long long* __restrict__ bits) {
  const int blk = blockIdx.x;
  if (blk < 288) {
    const float* w = (blk < 216) ? wq : wp;
    unsigned short* Bf = (blk < 216) ? Bfq : Bfp;
    const int t = ((blk < 216) ? blk : blk - 216) * 256 + threadIdx.x;
    const int fid = t >> 6, lc = t & 63;
    const int cg = fid / 24, ksl = fid - cg * 24;
    const int col = cg * 32 + (lc & 31);
    const int k = ksl * 16 + (lc >> 5) * 8;
    const float* src = w + (size_t)col * 384 + k;
    unsigned short* dst = Bf + ((size_t)fid << 9) + (lc << 3);
#pragma unroll
    for (int j = 0; j < 8; ++j) dst[j] = f2bf(src[j]);
  } else {
    const int idx = (blk - 288) * 256 + threadIdx.x;  // 0..4095
    const int wdw = idx >> 6, m = idx & 63;
    unsigned long long bm = 0ull;
    if (m < 49) {
      const float* mp = mask + (size_t)wdw * 2401 + (size_t)m * 49;
      for (int n = 0; n < 49; ++n)
        if (mp[n] > -50.f) bm |= (1ull << n);
    }
    bits[idx] = bm;
  }
}

// ---------------------------------------------------------------------------
// gemm_32: C = A * B^T (+bias). 32x32x16 MFMA, wave tile 64 x 96,
// 8 waves = 2M x 4N, acc[2][3] f32x16, 3-buffer B register rotation.
// MODE 0: A = fp32 x (fused cvt, conflict-free chunk map); planar qkv out.
// MODE 1: A = bf16 via global_load_lds; fp32 out (+bias).
// A-frag fid = (row/32)*24 + kslot; lane: row=rg*32+(l&31), k=ksl*16+(l>>5)*8.
// C/D map (verified): col = lane&31, row = (r&3) + 8*(r>>2) + 4*(lane>>5).
// ---------------------------------------------------------------------------
#define LB32(dst, ks_)                                                         \
  {                                                                            \
    _Pragma("unroll") for (int ni = 0; ni < 3; ++ni)                           \
        dst[ni] = *(const bfrag8*)(                                            \
            Bf + ((size_t)((cg0 + ni) * 24 + (ks_)) << 9) + (lane << 3));      \
  }

#define MF32(bb, ks_)                                                          \
  {                                                                            \
    const bfrag8 af0 = *(const bfrag8*)(Ab + ((size_t)(ks_) << 10));           \
    const bfrag8 af1 = *(const bfrag8*)(Ab + ((size_t)(24 + (ks_)) << 10));    \
    _Pragma("unroll") for (int ni = 0; ni < 3; ++ni) {                         \
      acc[0][ni] = __builtin_amdgcn_mfma_f32_32x32x16_bf16(af0, bb[ni],        \
                                                           acc[0][ni], 0, 0, 0);\
      acc[1][ni] = __builtin_amdgcn_mfma_f32_32x32x16_bf16(af1, bb[ni],        \
                                                           acc[1][ni], 0, 0, 0);\
    }                                                                          \
  }

template <int NR, int MODE, int SWZ>
__global__ void __launch_bounds__(512, 1) gemm_32(
    const float* __restrict__ Af32, const unsigned short* __restrict__ Abf,
    const unsigned short* __restrict__ Bf, const float* __restrict__ bias,
    unsigned short* __restrict__ qkv, float* __restrict__ f_out) {
  __shared__ __align__(16) unsigned short Alds[128 * 384];  // 96 KB frag-major

  int bid = blockIdx.x;
  bid = (bid & 7) * SWZ + (bid >> 3);      // XCD-contiguous (1568 = 8*196)
  const int tid = threadIdx.x;
  const int lane = tid & 63, w = tid >> 6;
  const int wr = w >> 2, wc = w & 3;       // 2 M-halves x 4 N-quarters
  const int l31 = lane & 31, l5 = lane >> 5;
  const size_t a_row0 = (size_t)bid * 128;

  if (MODE == 0) {
    // fused fp32 -> bf16 staging, conflict-free chunk map:
    // chunk c = tid + j*512, fid = w + j*8 (wave-uniform), write base+lane*16.
#pragma unroll
    for (int j = 0; j < 12; ++j) {
      const int fid = w + j * 8;
      const int rg = fid / 24, ksl = fid - rg * 24;
      const int row = rg * 32 + l31;
      const int k = ksl * 16 + l5 * 8;
      const float* src = Af32 + (a_row0 + row) * 384 + k;
      const float4 v0 = *(const float4*)(src);
      const float4 v1 = *(const float4*)(src + 4);
      bfrag8 h;
      h[0] = (short)f2bf(v0.x); h[1] = (short)f2bf(v0.y);
      h[2] = (short)f2bf(v0.z); h[3] = (short)f2bf(v0.w);
      h[4] = (short)f2bf(v1.x); h[5] = (short)f2bf(v1.y);
      h[6] = (short)f2bf(v1.z); h[7] = (short)f2bf(v1.w);
      *(bfrag8*)((char*)Alds + ((w << 10) + (j << 13)) + (lane << 4)) = h;
    }
  } else {
    // bf16 source: 6144 chunks of 16B via global_load_lds, 12/thread.
#pragma unroll
    for (int j = 0; j < 12; ++j) {
      const int fid = w + j * 8;
      const int rg = fid / 24, ksl = fid - rg * 24;
      const int row = rg * 32 + l31;
      const int k = ksl * 16 + l5 * 8;
      gload_lds16(Abf + (a_row0 + row) * 384 + k,
                  (char*)Alds + ((w << 10) + (j << 13)));  // wave-uniform base
    }
  }
  __syncthreads();                         // the ONLY barrier

  // af source: fid = (wr*2 + mi)*24 + ksl
  const char* Ab = (const char*)Alds + ((size_t)(wr * 48) << 10) + (lane << 4);

  for (int rnd = 0; rnd < NR; ++rnd) {
    const int cg0 = (rnd * 4 + wc) * 3;    // first 32-col group of this wave
    facc16 acc[2][3];
#pragma unroll
    for (int mi = 0; mi < 2; ++mi)
#pragma unroll
      for (int ni = 0; ni < 3; ++ni)
#pragma unroll
        for (int r = 0; r < 16; ++r) acc[mi][ni][r] = 0.f;

    bfrag8 bA[3], bB[3], bC[3];
    LB32(bA, 0);
    LB32(bB, 1);
    LB32(bC, 2);
#pragma unroll 1   // ROLLED: prevents load hoisting / register blowup
    for (int ks = 0; ks < 24; ks += 3) {
      MF32(bA, ks);
      if (ks + 3 < 24) LB32(bA, ks + 3);
      MF32(bB, ks + 1);
      if (ks + 4 < 24) LB32(bB, ks + 4);
      MF32(bC, ks + 2);
      if (ks + 5 < 24) LB32(bC, ks + 5);
    }

    // ---- epilogue: col = (cg0+ni)*32 + l31, m = a_row0 + wr*64 + mi*32 +
    //      (r&3) + 8*(r>>2) + 4*l5
    if (MODE == 0) {
#pragma unroll
      for (int ni = 0; ni < 3; ++ni) {
        const int j0 = (cg0 + ni) * 32;               // 32-aligned col base
        const int t = j0 / 384;
        const int rj = j0 - t * 384;
        const int h = rj >> 5;
        unsigned short* pl = qkv + (size_t)(t * 12 + h) * PLANE + l31;
        const float bvv = bias[j0 + l31];
        const float sc = (t == 0) ? SCALE_Q : 1.0f;
#pragma unroll
        for (int mi = 0; mi < 2; ++mi)
#pragma unroll
          for (int r = 0; r < 16; ++r) {
            const size_t m = a_row0 + wr * 64 + mi * 32 +
                             (r & 3) + 8 * (r >> 2) + 4 * l5;
            pl[m * 32] = f2bf((acc[mi][ni][r] + bvv) * sc);
          }
      }
    } else {
#pragma unroll
      for (int ni = 0; ni < 3; ++ni) {
        const int col = (cg0 + ni) * 32 + l31;
        const float bvv = bias[col];
#pragma unroll
        for (int mi = 0; mi < 2; ++mi)
#pragma unroll
          for (int r = 0; r < 16; ++r) {
            const size_t m = a_row0 + wr * 64 + mi * 32 +
                             (r & 3) + 8 * (r >> 2) + 4 * l5;
            f_out[m * 384 + col] = acc[mi][ni][r] + bvv;
          }
      }
    }
  }
}

// ---------------------------------------------------------------------------
// Attention: one wave per (window b, head h). Planar Q/K/V; Q/K frags direct
// from global; V staged to LDS transposed+swizzled; bitmask softmax.
// ---------------------------------------------------------------------------
__global__ void __launch_bounds__(64) attn_kernel(
    const unsigned short* __restrict__ QKV,        // 36 planes
    const unsigned long long* __restrict__ mbits,  // (64, 64)
    unsigned short* __restrict__ Og) {             // (4096*49, 384) bf16
  __shared__ unsigned short Vt[32 * 64];   // [d][n], byte-XOR swizzled
  __shared__ unsigned short Ps[64 * 64];   // [m][n], byte-XOR swizzled

  const int bid = blockIdx.x;
  const int b = bid / 12, h = bid - b * 12;
  const int lane = threadIdx.x;
  const int l15 = lane & 15, l4 = lane >> 4;

  const bfrag8 z8 = {0, 0, 0, 0, 0, 0, 0, 0};
  const facc4 fz = {0.f, 0.f, 0.f, 0.f};

  const size_t wb = (size_t)b * 49 * 32;
  const unsigned short* Qp = QKV + (size_t)h * PLANE + wb;
  const unsigned short* Kp = QKV + (size_t)(12 + h) * PLANE + wb;
  const unsigned short* Vp = QKV + (size_t)(24 + h) * PLANE + wb;

  // zero ALL of Vt (4096 B): pad cols n in [49,64) must be 0
#pragma unroll
  for (int i = 0; i < 4; ++i)
    *(bfrag8*)((char*)Vt + (lane + i * 64) * 16) = z8;

  // stage V -> Vt transposed (196 real 16B chunks)
#pragma unroll
  for (int i = 0; i < 4; ++i) {
    const int c = lane + i * 64;
    if (c < 196) {
      const bfrag8 vv = *(const bfrag8*)(Vp + c * 8);
      const int n = c >> 2, cc = c & 3;
      const int d0 = cc * 8;
#pragma unroll
      for (int jj = 0; jj < 8; ++jj) {
        const int d = d0 + jj;
        *(unsigned short*)((char*)Vt + (((d << 7) + (n << 1)) ^ ((d & 7) << 4))) =
            (unsigned short)vv[jj];
      }
    }
  }
  __syncthreads();

  // S = Q K^T : frags direct from global. frag[row=l15][k=l4*8+j]
  facc4 s[4][4];
  {
    bfrag8 qa[4], kf[4];
#pragma unroll
    for (int mi = 0; mi < 4; ++mi)
      qa[mi] = *(const bfrag8*)((const char*)Qp + (mi * 16 + l15) * 64 + l4 * 16);
#pragma unroll
    for (int ni = 0; ni < 4; ++ni)
      kf[ni] = *(const bfrag8*)((const char*)Kp + (ni * 16 + l15) * 64 + l4 * 16);
#pragma unroll
    for (int mi = 0; mi < 4; ++mi)
#pragma unroll
      for (int ni = 0; ni < 4; ++ni)
        s[mi][ni] = __builtin_amdgcn_mfma_f32_16x16x32_bf16(qa[mi], kf[ni], fz, 0, 0, 0);
  }

  // bitmask softmax. acc layout: n = ni*16 + l15, m = mi*16 + l4*4 + r
  const unsigned long long* mb = mbits + (size_t)(b & 63) * 64;
  float rinv[4][4];
#pragma unroll
  for (int mi = 0; mi < 4; ++mi)
#pragma unroll
    for (int r = 0; r < 4; ++r) {
      const int m = mi * 16 + l4 * 4 + r;
      const unsigned long long mw = mb[m];
      float mx = -1e30f;
      int ok[4];
#pragma unroll
      for (int ni = 0; ni < 4; ++ni) {
        const int n = ni * 16 + l15;
        ok[ni] = (int)((mw >> n) & 1ull);
        const float v = ok[ni] ? s[mi][ni][r] : -1e30f;
        mx = fmaxf(mx, v);
      }
      mx = fmaxf(mx, __shfl_xor(mx, 1));
      mx = fmaxf(mx, __shfl_xor(mx, 2));
      mx = fmaxf(mx, __shfl_xor(mx, 4));
      mx = fmaxf(mx, __shfl_xor(mx, 8));
      float sum = 0.f;
#pragma unroll
      for (int ni = 0; ni < 4; ++ni) {
        const float p = ok[ni] ? __expf(s[mi][ni][r] - mx) : 0.f;
        s[mi][ni][r] = p;
        sum += p;
      }
      sum += __shfl_xor(sum, 1);
      sum += __shfl_xor(sum, 2);
      sum += __shfl_xor(sum, 4);
      sum += __shfl_xor(sum, 8);
      rinv[mi][r] = 1.0f / sum;
#pragma unroll
      for (int ni = 0; ni < 4; ++ni) {
        const int n = ni * 16 + l15;
        *(unsigned short*)((char*)Ps + (((m << 7) + (n << 1)) ^ ((m & 7) << 4))) =
            f2bf(s[mi][ni][r]);
      }
    }
  __syncthreads();

  // O = P V (unnormalized), then scale by 1/rowsum
  facc4 o[4][2];
#pragma unroll
  for (int mi = 0; mi < 4; ++mi)
#pragma unroll
    for (int di = 0; di < 2; ++di) o[mi][di] = fz;
#pragma unroll
  for (int kk = 0; kk < 2; ++kk) {
    bfrag8 pa[4], vb[2];
#pragma unroll
    for (int mi = 0; mi < 4; ++mi) {
      const int row = mi * 16 + l15;
      pa[mi] = *(const bfrag8*)((const char*)Ps +
                                (((row << 7) + kk * 64 + (l4 << 4)) ^ ((row & 7) << 4)));
    }
#pragma unroll
    for (int di = 0; di < 2; ++di) {
      const int row = di * 16 + l15;
      vb[di] = *(const bfrag8*)((const char*)Vt +
                                (((row << 7) + kk * 64 + (l4 << 4)) ^ ((row & 7) << 4)));
    }
#pragma unroll
    for (int mi = 0; mi < 4; ++mi)
#pragma unroll
      for (int di = 0; di < 2; ++di)
        o[mi][di] = __builtin_amdgcn_mfma_f32_16x16x32_bf16(pa[mi], vb[di], o[mi][di], 0, 0, 0);
  }

  unsigned short* op = Og + (size_t)b * 18816 + h * 32;  // (b, n, C)
#pragma unroll
  for (int mi = 0; mi < 4; ++mi)
#pragma unroll
    for (int r = 0; r < 4; ++r) {
      const int m = mi * 16 + l4 * 4 + r;
      if (m < 49) {
        const float rs = rinv[mi][r];
#pragma unroll
        for (int di = 0; di < 2; ++di)
          op[(size_t)m * 384 + di * 16 + l15] = f2bf(o[mi][di][r] * rs);
      }
    }
}

// ---------------------------------------------------------------------------
extern "C" void kernel_launch(void* const* d_in, const int* in_sizes, int n_in,
                              void* d_out, int out_size, void* d_ws, size_t ws_size,
                              hipStream_t stream) {
  const float* x      = (const float*)d_in[0];  // (4096, 49, 384)
  const float* mask   = (const float*)d_in[1];  // (64, 49, 49)
  const float* w_qkv  = (const float*)d_in[2];  // (1152, 384)
  const float* b_qkv  = (const float*)d_in[3];  // (1152,)
  const float* w_proj = (const float*)d_in[4];  // (384, 384)
  const float* b_proj = (const float*)d_in[5];  // (384,)
  float* out = (float*)d_out;

  const size_t E = 77070336ull;  // 200704*384  (3*E = 36 planes)
  unsigned short* wsu   = (unsigned short*)d_ws;
  unsigned short* qkvp  = wsu;            // planar qkv: 3E
  unsigned short* o_ws  = wsu + 3 * E;    // (200704, 384) bf16
  unsigned short* Bfq   = wsu + 4 * E;    // frag-major W_qkv bf16 (442368)
  unsigned short* Bfp   = Bfq + 442368ull;  // frag-major W_proj bf16 (147456)
  unsigned long long* mb = (unsigned long long*)(Bfp + 147456ull);  // 4096 u64
  const size_t need = (4 * E + 442368ull + 147456ull) * 2ull + 4096ull * 8ull;
  if (ws_size < need) {
    fprintf(stderr, "[WindowAttention] ws too small: need=%zu have=%zu\n",
            (size_t)need, ws_size);
    return;
  }

  // prep: 288 blocks wswz32 (Bfq 864 frags, Bfp 288 frags) + 16 blocks mask
  prep_kernel<<<304, 256, 0, stream>>>(w_qkv, w_proj, mask, Bfq, Bfp, mb);

  // QKV projection (fused fp32->bf16 A-stage): 1568 blocks, 3 rounds x 96
  gemm_32<3, 0, 196><<<1568, 512, 0, stream>>>(x, nullptr, Bfq, b_qkv,
                                               qkvp, nullptr);

  // attention: one wave per (b, h)
  attn_kernel<<<49152, 64, 0, stream>>>(qkvp, mb, o_ws);

  // output projection: 1 round x 4 waves x 96 = 384
  gemm_32<1, 1, 196><<<1568, 512, 0, stream>>>(nullptr, o_ws, Bfp, b_proj,
                                               nullptr, out);
}